// Round 7
// baseline (532.048 us; speedup 1.0000x reference)
//
#include <hip/hip_runtime.h>

#define N_NODES 50000
#define N_EDGES 800000
#define HID 128
#define OUTD 10
#define HOPS 4
#define NGRAPH 128
#define CAP 64
#define OVF_MAX 4096
#define GBM 128         // rows per GEMM block
#define EPT 4           // edges/thread in fused fill: 391 * 256 * 4 = 400384 >= 400000

// ---------- int64-vs-int32 layout probe ----------
__global__ void detect_kernel(const int* __restrict__ ei, int* __restrict__ flag) {
  if (threadIdx.x == 0 && blockIdx.x == 0) {
    int all0 = 1;
    for (int i = 0; i < 64; ++i) {
      if (ei[2 * i + 1] != 0) { all0 = 0; break; }
    }
    flag[0] = all0;
  }
}

__device__ __forceinline__ int ld_idx(const int* p, int i, int is64) {
  return is64 ? p[2 * i] : p[i];
}

__global__ void dinv_kernel(const int* __restrict__ fillcnt, float* __restrict__ dinv) {
  int i = blockIdx.x * blockDim.x + threadIdx.x;
  if (i < N_NODES) dinv[i] = 1.0f / sqrtf(1.0f + (float)fillcnt[i]);
}

// ---------- fold classifier through last (linear) hop: Wf = W4 @ Wc, bf = b4 @ Wc + bc ----------
__global__ void foldw_kernel(const float* __restrict__ W4, const float* __restrict__ Wc,
                             const float* __restrict__ b4, const float* __restrict__ bc,
                             float* __restrict__ Wf, float* __restrict__ bf) {
  int tid = threadIdx.x;
  for (int idx = tid; idx < HID * OUTD; idx += 256) {
    int k = idx / OUTD, o = idx % OUTD;
    float s = 0.f;
    for (int j = 0; j < HID; ++j) s += W4[k * HID + j] * Wc[j * OUTD + o];
    Wf[idx] = s;
  }
  if (tid < OUTD) {
    float s = bc[tid];
    for (int j = 0; j < HID; ++j) s += b4[j] * Wc[j * OUTD + tid];
    bf[tid] = s;
  }
}

// ---------- GEMM body v3: 128x64 tile, 256 threads, 8x4 per-thread; W-half in LDS ----------
__device__ __forceinline__ void gemm_body(const float* __restrict__ A,
                                          const float* __restrict__ W,
                                          const float* __restrict__ bias,
                                          float* __restrict__ C, int M,
                                          int row0, int col0) {
  __shared__ float sW[HID * 64];   // 32 KB -> 5 blocks/CU
  int tid = threadIdx.x;

#pragma unroll
  for (int it = 0; it < 8; ++it) {
    int f = it * 256 + tid;            // 0..2047
    int k = f >> 4;
    int c4 = (f & 15) << 2;
    *(float4*)&sW[k * 64 + c4] = *(const float4*)(W + (size_t)k * HID + col0 + c4);
  }
  __syncthreads();

  int tc = tid & 15, tr = tid >> 4;    // tr 0..15 -> rows tr*8..tr*8+7
  int cc = tc * 4;
  int r0 = row0 + tr * 8;
  int off[8];
#pragma unroll
  for (int i = 0; i < 8; ++i) off[i] = min(r0 + i, M - 1) * 32;   // float4 row offsets
  const float4* A4 = (const float4*)A;

  float acc[8][4];
#pragma unroll
  for (int i = 0; i < 8; ++i)
#pragma unroll
    for (int j = 0; j < 4; ++j) acc[i][j] = 0.f;

#pragma unroll 4
  for (int k4 = 0; k4 < 32; ++k4) {
    float4 a[8];
#pragma unroll
    for (int i = 0; i < 8; ++i) a[i] = A4[off[i] + k4];
#pragma unroll
    for (int kk = 0; kk < 4; ++kk) {
      float4 w = *(const float4*)&sW[(4 * k4 + kk) * 64 + cc];
#pragma unroll
      for (int i = 0; i < 8; ++i) {
        float x = (kk == 0) ? a[i].x : (kk == 1) ? a[i].y : (kk == 2) ? a[i].z : a[i].w;
        acc[i][0] += x * w.x; acc[i][1] += x * w.y;
        acc[i][2] += x * w.z; acc[i][3] += x * w.w;
      }
    }
  }

  float4 bv = make_float4(0.f, 0.f, 0.f, 0.f);
  if (bias) bv = *(const float4*)(bias + col0 + cc);
#pragma unroll
  for (int i = 0; i < 8; ++i) {
    int gr = r0 + i;
    if (gr < M) {
      float4 o;
      o.x = acc[i][0] + bv.x; o.y = acc[i][1] + bv.y;
      o.z = acc[i][2] + bv.z; o.w = acc[i][3] + bv.w;
      *(float4*)(C + (size_t)gr * HID + col0 + cc) = o;
    }
  }
}

__global__ __launch_bounds__(256) void gemm_kernel(const float* __restrict__ A,
                                                   const float* __restrict__ W,
                                                   const float* __restrict__ bias,
                                                   float* __restrict__ C, int M) {
  gemm_body(A, W, bias, C, M, blockIdx.x * GBM, blockIdx.y * 64);
}

// ---------- GEMM fused with CSR fill over edge range [e0,e1) (y==0 blocks) ----------
__global__ __launch_bounds__(256) void gemm_fill_kernel(const float* __restrict__ A,
                                                        const float* __restrict__ W,
                                                        const float* __restrict__ bias,
                                                        float* __restrict__ C,
                                                        const int* __restrict__ ei,
                                                        int* __restrict__ fillcnt,
                                                        int* __restrict__ col_fixed,
                                                        int* __restrict__ ovf_cnt,
                                                        int* __restrict__ ovf,
                                                        const int* __restrict__ flag,
                                                        int e0, int e1) {
  if (blockIdx.y == 0) {
    int is64 = flag[0];
    int tid = threadIdx.x;
    int base = e0 + blockIdx.x * (256 * EPT);
    int dsts[EPT], srcs[EPT], pos[EPT];
#pragma unroll
    for (int u = 0; u < EPT; ++u) {
      int e = base + u * 256 + tid;
      if (e < e1) {
        dsts[u] = ld_idx(ei, N_EDGES + e, is64);
        srcs[u] = ld_idx(ei, e, is64);
      } else {
        dsts[u] = -1; srcs[u] = 0;
      }
    }
#pragma unroll
    for (int u = 0; u < EPT; ++u)
      pos[u] = (dsts[u] >= 0) ? atomicAdd(&fillcnt[dsts[u]], 1) : 0;
#pragma unroll
    for (int u = 0; u < EPT; ++u) {
      if (dsts[u] >= 0) {
        if (pos[u] < CAP) {
          col_fixed[dsts[u] * CAP + pos[u]] = srcs[u];
        } else {
          int o = atomicAdd(ovf_cnt, 1);
          if (o < OVF_MAX) { ovf[2 * o] = dsts[u]; ovf[2 * o + 1] = srcs[u]; }
        }
      }
    }
  }
  gemm_body(A, W, bias, C, N_NODES, blockIdx.x * GBM, blockIdx.y * 64);
}

// ---------- GCN aggregate v2: 2 neighbors/wave via 32-lane halves, float4 lanes ----------
__global__ __launch_bounds__(256) void agg_kernel(const float* __restrict__ xw,
                                                  const int* __restrict__ fillcnt,
                                                  const int* __restrict__ col_fixed,
                                                  const float* __restrict__ dinv,
                                                  const float* __restrict__ bias,
                                                  const int* __restrict__ ovf_cnt,
                                                  const int* __restrict__ ovf,
                                                  float* __restrict__ out, int relu) {
  int wave = threadIdx.x >> 6;
  int lane = threadIdx.x & 63;
  int node = blockIdx.x * 4 + wave;
  if (node >= N_NODES) return;
  int h = lane >> 5;        // half: 0 or 1
  int q = lane & 31;        // float4 feature chunk

  const float4* x4 = (const float4*)xw;
  float di = dinv[node];
  float4 acc = make_float4(0.f, 0.f, 0.f, 0.f);
  if (h == 0) {             // self term + bias once
    float sn = di * di;
    float4 v = x4[(size_t)node * 32 + q];
    float4 b = ((const float4*)bias)[q];
    acc.x = v.x * sn + b.x; acc.y = v.y * sn + b.y;
    acc.z = v.z * sn + b.z; acc.w = v.w * sn + b.w;
  }

  int deg = fillcnt[node];
  int m = min(deg, CAP);
  int cidx = 0;
  float cw = 0.f;
  if (lane < m) {
    cidx = col_fixed[node * CAP + lane];
    cw = dinv[cidx];
  }

#pragma unroll 2
  for (int jj = 0; jj < m; jj += 2) {
    int s0 = __builtin_amdgcn_readlane(cidx, jj);
    int s1 = __builtin_amdgcn_readlane(cidx, jj + 1);
    float w0 = __uint_as_float((unsigned)__builtin_amdgcn_readlane((int)__float_as_uint(cw), jj));
    float w1 = __uint_as_float((unsigned)__builtin_amdgcn_readlane((int)__float_as_uint(cw), jj + 1));
    int src = h ? s1 : s0;
    float wv = (h ? w1 : w0) * di;
    if (jj + h < m) {
      float4 u = x4[(size_t)src * 32 + q];
      acc.x += u.x * wv; acc.y += u.y * wv;
      acc.z += u.z * wv; acc.w += u.w * wv;
    }
  }

  if (deg > CAP && h == 0) {   // rare overflow fixup, half0 only
    int novf = min(*ovf_cnt, OVF_MAX);
    for (int o = 0; o < novf; ++o) {
      if (ovf[2 * o] == node) {
        int src = ovf[2 * o + 1];
        float w = dinv[src] * di;
        float4 u = x4[(size_t)src * 32 + q];
        acc.x += u.x * w; acc.y += u.y * w;
        acc.z += u.z * w; acc.w += u.w * w;
      }
    }
  }

  // combine halves
  float4 o;
  o.x = __shfl_xor(acc.x, 32, 64);
  o.y = __shfl_xor(acc.y, 32, 64);
  o.z = __shfl_xor(acc.z, 32, 64);
  o.w = __shfl_xor(acc.w, 32, 64);
  acc.x += o.x; acc.y += o.y; acc.z += o.z; acc.w += o.w;

  if (h == 0) {
    if (relu) {
      acc.x = fmaxf(acc.x, 0.f); acc.y = fmaxf(acc.y, 0.f);
      acc.z = fmaxf(acc.z, 0.f); acc.w = fmaxf(acc.w, 0.f);
    }
    ((float4*)out)[(size_t)node * 32 + q] = acc;
  }
}

// ---------- z = h3 @ Wf  (50000 x 128 @ 128 x 10) ----------
__global__ __launch_bounds__(256) void z_kernel(const float* __restrict__ h,
                                                const float* __restrict__ Wf,
                                                float* __restrict__ z, int M) {
  __shared__ float sW[HID * OUTD];
  int tid = threadIdx.x;
  for (int i = tid; i < HID * OUTD; i += 256) sW[i] = Wf[i];
  __syncthreads();
  int row = blockIdx.x * 256 + tid;
  if (row >= M) return;
  float y[OUTD];
#pragma unroll
  for (int o = 0; o < OUTD; ++o) y[o] = 0.f;
  const float4* hr = (const float4*)(h + (size_t)row * HID);
  for (int k4 = 0; k4 < 32; ++k4) {
    float4 hv = hr[k4];
    int kb = k4 * 4;
#pragma unroll
    for (int o = 0; o < OUTD; ++o) {
      y[o] += hv.x * sW[(kb + 0) * OUTD + o];
      y[o] += hv.y * sW[(kb + 1) * OUTD + o];
      y[o] += hv.z * sW[(kb + 2) * OUTD + o];
      y[o] += hv.w * sW[(kb + 3) * OUTD + o];
    }
  }
#pragma unroll
  for (int o = 0; o < OUTD; ++o) z[(size_t)row * OUTD + o] = y[o];
}

// ---------- last hop in 10-dim + per-graph mean pooling ----------
__global__ __launch_bounds__(256) void agg10_kernel(const float* __restrict__ z,
                                                    const int* __restrict__ fillcnt,
                                                    const int* __restrict__ col_fixed,
                                                    const float* __restrict__ dinv,
                                                    const float* __restrict__ bf,
                                                    const int* __restrict__ ovf_cnt,
                                                    const int* __restrict__ ovf,
                                                    const int* __restrict__ batch,
                                                    float* __restrict__ pool,
                                                    float* __restrict__ cnt,
                                                    const int* __restrict__ flag) {
  __shared__ float spool[NGRAPH * OUTD];
  __shared__ float scount[NGRAPH];
  int tid = threadIdx.x;
  for (int i = tid; i < NGRAPH * OUTD; i += 256) spool[i] = 0.f;
  if (tid < NGRAPH) scount[tid] = 0.f;
  __syncthreads();

  int is64 = flag[0];
  int node = blockIdx.x * 256 + tid;
  bool valid = node < N_NODES;
  int nc = valid ? node : (N_NODES - 1);
  int g = ld_idx(batch, nc, is64);

  float acc[OUTD];
#pragma unroll
  for (int o = 0; o < OUTD; ++o) acc[o] = 0.f;
  float c = 0.f;

  if (valid) {
    float di = dinv[node];
    float sn = di * di;
#pragma unroll
    for (int o = 0; o < OUTD; ++o) acc[o] = z[(size_t)node * OUTD + o] * sn + bf[o];
    c = 1.f;

    int deg = fillcnt[node];
    int m = min(deg, CAP);
    for (int j = 0; j < m; ++j) {
      int src = col_fixed[node * CAP + j];
      float w = dinv[src] * di;
      const float2* zr = (const float2*)(z + (size_t)src * OUTD);
#pragma unroll
      for (int p = 0; p < 5; ++p) {
        float2 u = zr[p];
        acc[2 * p] += u.x * w;
        acc[2 * p + 1] += u.y * w;
      }
    }
    if (deg > CAP) {
      int novf = min(*ovf_cnt, OVF_MAX);
      for (int o = 0; o < novf; ++o) {
        if (ovf[2 * o] == node) {
          int src = ovf[2 * o + 1];
          float w = dinv[src] * di;
#pragma unroll
          for (int qq = 0; qq < OUTD; ++qq) acc[qq] += z[(size_t)src * OUTD + qq] * w;
        }
      }
    }
  }

  // pooling: wave-uniform fast path (batch sorted)
  int g0 = __builtin_amdgcn_readfirstlane(g);
  unsigned long long same = __ballot(g == g0);
  unsigned long long act = __ballot(1);
  if (same == act) {
#pragma unroll
    for (int off = 1; off < 64; off <<= 1) {
#pragma unroll
      for (int o = 0; o < OUTD; ++o) acc[o] += __shfl_xor(acc[o], off, 64);
      c += __shfl_xor(c, off, 64);
    }
    if ((tid & 63) == 0) {
#pragma unroll
      for (int o = 0; o < OUTD; ++o) atomicAdd(&spool[g0 * OUTD + o], acc[o]);
      atomicAdd(&scount[g0], c);
    }
  } else if (valid) {
#pragma unroll
    for (int o = 0; o < OUTD; ++o) atomicAdd(&spool[g * OUTD + o], acc[o]);
    atomicAdd(&scount[g], 1.f);
  }
  __syncthreads();
  for (int i = tid; i < NGRAPH * OUTD; i += 256) {
    float v = spool[i];
    if (v != 0.f) atomicAdd(&pool[i], v);
  }
  if (tid < NGRAPH && scount[tid] != 0.f) atomicAdd(&cnt[tid], scount[tid]);
}

__global__ void finalize_kernel(const float* __restrict__ pool,
                                const float* __restrict__ cnt,
                                float* __restrict__ out) {
  int i = blockIdx.x * blockDim.x + threadIdx.x;
  if (i < NGRAPH * OUTD) {
    float c = cnt[i / OUTD];
    out[i] = pool[i] / fmaxf(c, 1.0f);
  }
}

extern "C" void kernel_launch(void* const* d_in, const int* in_sizes, int n_in,
                              void* d_out, int out_size, void* d_ws, size_t ws_size,
                              hipStream_t stream) {
  const float* x      = (const float*)d_in[0];
  const int*   ei     = (const int*)d_in[1];
  const int*   batch  = (const int*)d_in[2];
  const float* W_in   = (const float*)d_in[3];
  const float* b_in   = (const float*)d_in[4];
  const float* W_hops = (const float*)d_in[5];
  const float* b_hops = (const float*)d_in[6];
  const float* W_cls  = (const float*)d_in[7];
  const float* b_cls  = (const float*)d_in[8];
  float* out = (float*)d_out;

  char* ws = (char*)d_ws;
  size_t off = 0;
  auto alloc = [&](size_t bytes) -> void* {
    void* p = ws + off;
    off += (bytes + 255) & ~(size_t)255;
    return p;
  };

  // zero-initialized region first
  int*   fillcnt = (int*)alloc(N_NODES * 4);
  int*   ovf_cnt = (int*)alloc(4);
  float* pool    = (float*)alloc(NGRAPH * OUTD * 4);
  float* cnt     = (float*)alloc(NGRAPH * 4);
  size_t zero_bytes = off;
  int*   flag    = (int*)alloc(4);
  float* dinv    = (float*)alloc(N_NODES * 4);
  int*   ovf     = (int*)alloc(OVF_MAX * 2 * 4);
  int*   col_fixed = (int*)alloc((size_t)N_NODES * CAP * 4);
  float* bufA    = (float*)alloc((size_t)N_NODES * HID * 4);
  float* bufB    = (float*)alloc((size_t)N_NODES * HID * 4);
  float* z       = (float*)alloc((size_t)N_NODES * OUTD * 4);
  float* Wf      = (float*)alloc(HID * OUTD * 4);
  float* bf      = (float*)alloc(16 * 4);
  (void)ws_size; (void)in_sizes; (void)n_in; (void)out_size;

  hipMemsetAsync(d_ws, 0, zero_bytes, stream);
  detect_kernel<<<1, 64, 0, stream>>>(ei, flag);
  foldw_kernel<<<1, 256, 0, stream>>>(W_hops + 3 * (size_t)HID * HID, W_cls,
                                      b_hops + 3 * HID, b_cls, Wf, bf);

  dim3 ggrid((N_NODES + GBM - 1) / GBM, 2);   // (391, 2)
  const int EHALF = N_EDGES / 2;              // 400000

  // encoder GEMM + first half of edge placement
  gemm_fill_kernel<<<ggrid, 256, 0, stream>>>(x, W_in, b_in, bufA,
                                              ei, fillcnt, col_fixed, ovf_cnt, ovf, flag,
                                              0, EHALF);
  // hop-1 GEMM + second half of edge placement
  gemm_fill_kernel<<<ggrid, 256, 0, stream>>>(bufA, W_hops, nullptr, bufB,
                                              ei, fillcnt, col_fixed, ovf_cnt, ovf, flag,
                                              EHALF, N_EDGES);
  dinv_kernel<<<(N_NODES + 255) / 256, 256, 0, stream>>>(fillcnt, dinv);

  // hop 1 aggregate
  agg_kernel<<<(N_NODES + 3) / 4, 256, 0, stream>>>(bufB, fillcnt, col_fixed, dinv,
                                                    b_hops, ovf_cnt, ovf, bufA, 1);
  // hops 2..3
  for (int i = 1; i < 3; ++i) {
    gemm_kernel<<<ggrid, 256, 0, stream>>>(bufA, W_hops + (size_t)i * HID * HID, nullptr, bufB, N_NODES);
    agg_kernel<<<(N_NODES + 3) / 4, 256, 0, stream>>>(bufB, fillcnt, col_fixed, dinv,
                                                      b_hops + (size_t)i * HID, ovf_cnt, ovf,
                                                      bufA, 1);
  }

  // hop 4 folded through classifier (no ReLU): z = h3 @ (W4@Wc); y = agg(z) + bf; pool
  int nb = (N_NODES + 255) / 256;
  z_kernel<<<nb, 256, 0, stream>>>(bufA, Wf, z, N_NODES);
  agg10_kernel<<<nb, 256, 0, stream>>>(z, fillcnt, col_fixed, dinv, bf,
                                       ovf_cnt, ovf, batch, pool, cnt, flag);
  finalize_kernel<<<(NGRAPH * OUTD + 255) / 256, 256, 0, stream>>>(pool, cnt, out);
}

// Round 8
// 460.342 us; speedup vs baseline: 1.1558x; 1.1558x over previous
//
#include <hip/hip_runtime.h>

#define N_NODES 50000
#define N_EDGES 800000
#define HID 128
#define OUTD 10
#define NGRAPH 128
#define CAP 64
#define OVF_MAX 4096
#define GBM 64          // rows per MFMA GEMM block
#define EPT 2           // edges/thread per fused fill half: 782*256*2 = 400384 >= 400000

typedef __attribute__((ext_vector_type(8))) short short8;
typedef __attribute__((ext_vector_type(4))) float f32x4;

// ---------- int64-vs-int32 layout probe ----------
__global__ void detect_kernel(const int* __restrict__ ei, int* __restrict__ flag) {
  if (threadIdx.x == 0 && blockIdx.x == 0) {
    int all0 = 1;
    for (int i = 0; i < 64; ++i) {
      if (ei[2 * i + 1] != 0) { all0 = 0; break; }
    }
    flag[0] = all0;
  }
}

__device__ __forceinline__ int ld_idx(const int* p, int i, int is64) {
  return is64 ? p[2 * i] : p[i];
}

__global__ void dinv_kernel(const int* __restrict__ fillcnt, float* __restrict__ dinv) {
  int i = blockIdx.x * blockDim.x + threadIdx.x;
  if (i < N_NODES) dinv[i] = 1.0f / sqrtf(1.0f + (float)fillcnt[i]);
}

// ---------- fold classifier through last (linear) hop ----------
__global__ void foldw_kernel(const float* __restrict__ W4, const float* __restrict__ Wc,
                             const float* __restrict__ b4, const float* __restrict__ bc,
                             float* __restrict__ Wf, float* __restrict__ bf) {
  int tid = threadIdx.x;
  for (int idx = tid; idx < HID * OUTD; idx += 256) {
    int k = idx / OUTD, o = idx % OUTD;
    float s = 0.f;
    for (int j = 0; j < HID; ++j) s += W4[k * HID + j] * Wc[j * OUTD + o];
    Wf[idx] = s;
  }
  if (tid < OUTD) {
    float s = bc[tid];
    for (int j = 0; j < HID; ++j) s += b4[j] * Wc[j * OUTD + tid];
    bf[tid] = s;
  }
}

// ---------- rne fp32 -> bf16 split ----------
__device__ __forceinline__ void split1(float v, unsigned& hb, unsigned& lb) {
  unsigned u = __float_as_uint(v);
  hb = (u + 0x7FFFu + ((u >> 16) & 1u)) >> 16;
  float r = v - __uint_as_float(hb << 16);
  unsigned ur = __float_as_uint(r);
  lb = (ur + 0x7FFFu + ((ur >> 16) & 1u)) >> 16;
}

// ---------- prep: weights -> bf16 hi/lo, transposed [n][k] ----------
// matrices: 0 = W_in, 1..3 = W_hops[0..2]
__global__ __launch_bounds__(256) void prep_kernel(const float* __restrict__ W_in,
                                                   const float* __restrict__ W_hops,
                                                   unsigned short* __restrict__ WhiT,
                                                   unsigned short* __restrict__ WloT) {
  int m = blockIdx.x;
  const float* W = (m == 0) ? W_in : (W_hops + (size_t)(m - 1) * HID * HID);
  unsigned short* oh = WhiT + (size_t)m * HID * HID;
  unsigned short* ol = WloT + (size_t)m * HID * HID;
  int tid = threadIdx.x;
  for (int it = 0; it < 64; ++it) {
    int idx = it * 256 + tid;          // 0..16383
    int k = idx >> 7, n = idx & 127;
    unsigned hb, lb;
    split1(W[k * HID + n], hb, lb);
    oh[n * HID + k] = (unsigned short)hb;   // transposed scatter (L2-absorbed, once)
    ol[n * HID + k] = (unsigned short)lb;
  }
}

// ---------- MFMA GEMM body: 64 rows x 128 cols/block, bf16x3, fp32 out ----------
__device__ __forceinline__ void gemm_mfma_body(const float* __restrict__ A,
                                               const unsigned short* __restrict__ WhT,
                                               const unsigned short* __restrict__ WlT,
                                               const float* __restrict__ bias,
                                               float* __restrict__ C, int M, int row0) {
  __shared__ unsigned short sBhi[HID * HID];   // [n][k], 16B-chunk XOR swizzle
  __shared__ unsigned short sBlo[HID * HID];
  int tid = threadIdx.x;

  // stage B hi/lo: 2048 chunks of 16B each, swizzled chunk index c^= (n&15)
#pragma unroll
  for (int it = 0; it < 8; ++it) {
    int f = it * 256 + tid;            // 0..2047
    int n = f >> 4, c = f & 15;
    int cs = c ^ (n & 15);
    *(uint4*)&sBhi[n * HID + cs * 8] = *(const uint4*)(WhT + n * HID + c * 8);
    *(uint4*)&sBlo[n * HID + cs * 8] = *(const uint4*)(WlT + n * HID + c * 8);
  }
  __syncthreads();

  int w = tid >> 6, lane = tid & 63;
  int m = lane & 15, kq = lane >> 4;           // A: row=m, k-group=kq
  int arow = min(row0 + w * 16 + m, M - 1);
  const float* Ap = A + (size_t)arow * HID + kq * 8;

  f32x4 acc[8];
#pragma unroll
  for (int j = 0; j < 8; ++j) acc[j] = (f32x4){0.f, 0.f, 0.f, 0.f};

#pragma unroll
  for (int k0 = 0; k0 < HID; k0 += 32) {
    float4 a0 = *(const float4*)(Ap + k0);
    float4 a1 = *(const float4*)(Ap + k0 + 4);
    float av[8] = {a0.x, a0.y, a0.z, a0.w, a1.x, a1.y, a1.z, a1.w};
    short8 ahi, alo;
#pragma unroll
    for (int i = 0; i < 8; ++i) {
      unsigned hb, lb;
      split1(av[i], hb, lb);
      ahi[i] = (short)hb;
      alo[i] = (short)lb;
    }
    int kc = (k0 >> 3) + kq;                   // k chunk index 0..15
    int cs = kc ^ m;
#pragma unroll
    for (int j = 0; j < 8; ++j) {
      int n = j * 16 + m;
      short8 bhi = *(const short8*)&sBhi[n * HID + cs * 8];
      short8 blo = *(const short8*)&sBlo[n * HID + cs * 8];
      acc[j] = __builtin_amdgcn_mfma_f32_16x16x32_bf16(ahi, bhi, acc[j], 0, 0, 0);
      acc[j] = __builtin_amdgcn_mfma_f32_16x16x32_bf16(alo, bhi, acc[j], 0, 0, 0);
      acc[j] = __builtin_amdgcn_mfma_f32_16x16x32_bf16(ahi, blo, acc[j], 0, 0, 0);
    }
  }

  // C/D: col = lane&15, row = (lane>>4)*4 + r
  int rbase = row0 + w * 16 + (lane >> 4) * 4;
#pragma unroll
  for (int j = 0; j < 8; ++j) {
    int col = j * 16 + m;
    float bv = bias ? bias[col] : 0.f;
#pragma unroll
    for (int r = 0; r < 4; ++r) {
      int row = rbase + r;
      if (row < M) C[(size_t)row * HID + col] = acc[j][r] + bv;
    }
  }
}

__global__ __launch_bounds__(256) void gemm_kernel(const float* __restrict__ A,
                                                   const unsigned short* __restrict__ WhT,
                                                   const unsigned short* __restrict__ WlT,
                                                   float* __restrict__ C, int M) {
  gemm_mfma_body(A, WhT, WlT, nullptr, C, M, blockIdx.x * GBM);
}

// ---------- MFMA GEMM fused with CSR fill over edge range [e0,e1) ----------
__global__ __launch_bounds__(256) void gemm_fill_kernel(const float* __restrict__ A,
                                                        const unsigned short* __restrict__ WhT,
                                                        const unsigned short* __restrict__ WlT,
                                                        const float* __restrict__ bias,
                                                        float* __restrict__ C,
                                                        const int* __restrict__ ei,
                                                        int* __restrict__ fillcnt,
                                                        int* __restrict__ col_fixed,
                                                        int* __restrict__ ovf_cnt,
                                                        int* __restrict__ ovf,
                                                        const int* __restrict__ flag,
                                                        int e0, int e1) {
  {
    int is64 = flag[0];
    int tid = threadIdx.x;
    int base = e0 + blockIdx.x * (256 * EPT);
    int dsts[EPT], srcs[EPT], pos[EPT];
#pragma unroll
    for (int u = 0; u < EPT; ++u) {
      int e = base + u * 256 + tid;
      if (e < e1) {
        dsts[u] = ld_idx(ei, N_EDGES + e, is64);
        srcs[u] = ld_idx(ei, e, is64);
      } else {
        dsts[u] = -1; srcs[u] = 0;
      }
    }
#pragma unroll
    for (int u = 0; u < EPT; ++u)
      pos[u] = (dsts[u] >= 0) ? atomicAdd(&fillcnt[dsts[u]], 1) : 0;
#pragma unroll
    for (int u = 0; u < EPT; ++u) {
      if (dsts[u] >= 0) {
        if (pos[u] < CAP) {
          col_fixed[dsts[u] * CAP + pos[u]] = srcs[u];
        } else {
          int o = atomicAdd(ovf_cnt, 1);
          if (o < OVF_MAX) { ovf[2 * o] = dsts[u]; ovf[2 * o + 1] = srcs[u]; }
        }
      }
    }
  }
  gemm_mfma_body(A, WhT, WlT, bias, C, N_NODES, blockIdx.x * GBM);
}

// ---------- GCN aggregate: 2 neighbors/wave via 32-lane halves, float4 lanes ----------
__global__ __launch_bounds__(256) void agg_kernel(const float* __restrict__ xw,
                                                  const int* __restrict__ fillcnt,
                                                  const int* __restrict__ col_fixed,
                                                  const float* __restrict__ dinv,
                                                  const float* __restrict__ bias,
                                                  const int* __restrict__ ovf_cnt,
                                                  const int* __restrict__ ovf,
                                                  float* __restrict__ out, int relu) {
  int wave = threadIdx.x >> 6;
  int lane = threadIdx.x & 63;
  int node = blockIdx.x * 4 + wave;
  if (node >= N_NODES) return;
  int h = lane >> 5;
  int q = lane & 31;

  const float4* x4 = (const float4*)xw;
  float di = dinv[node];
  float4 acc = make_float4(0.f, 0.f, 0.f, 0.f);
  if (h == 0) {
    float sn = di * di;
    float4 v = x4[(size_t)node * 32 + q];
    float4 b = ((const float4*)bias)[q];
    acc.x = v.x * sn + b.x; acc.y = v.y * sn + b.y;
    acc.z = v.z * sn + b.z; acc.w = v.w * sn + b.w;
  }

  int deg = fillcnt[node];
  int m = min(deg, CAP);
  int cidx = 0;
  float cw = 0.f;
  if (lane < m) {
    cidx = col_fixed[node * CAP + lane];
    cw = dinv[cidx];
  }

#pragma unroll 2
  for (int jj = 0; jj < m; jj += 2) {
    int s0 = __builtin_amdgcn_readlane(cidx, jj);
    int s1 = __builtin_amdgcn_readlane(cidx, jj + 1);
    float w0 = __uint_as_float((unsigned)__builtin_amdgcn_readlane((int)__float_as_uint(cw), jj));
    float w1 = __uint_as_float((unsigned)__builtin_amdgcn_readlane((int)__float_as_uint(cw), jj + 1));
    int src = h ? s1 : s0;
    float wv = (h ? w1 : w0) * di;
    if (jj + h < m) {
      float4 u = x4[(size_t)src * 32 + q];
      acc.x += u.x * wv; acc.y += u.y * wv;
      acc.z += u.z * wv; acc.w += u.w * wv;
    }
  }

  if (deg > CAP && h == 0) {
    int novf = min(*ovf_cnt, OVF_MAX);
    for (int o = 0; o < novf; ++o) {
      if (ovf[2 * o] == node) {
        int src = ovf[2 * o + 1];
        float w = dinv[src] * di;
        float4 u = x4[(size_t)src * 32 + q];
        acc.x += u.x * w; acc.y += u.y * w;
        acc.z += u.z * w; acc.w += u.w * w;
      }
    }
  }

  float4 o;
  o.x = __shfl_xor(acc.x, 32, 64);
  o.y = __shfl_xor(acc.y, 32, 64);
  o.z = __shfl_xor(acc.z, 32, 64);
  o.w = __shfl_xor(acc.w, 32, 64);
  acc.x += o.x; acc.y += o.y; acc.z += o.z; acc.w += o.w;

  if (h == 0) {
    if (relu) {
      acc.x = fmaxf(acc.x, 0.f); acc.y = fmaxf(acc.y, 0.f);
      acc.z = fmaxf(acc.z, 0.f); acc.w = fmaxf(acc.w, 0.f);
    }
    ((float4*)out)[(size_t)node * 32 + q] = acc;
  }
}

// ---------- z = h3 @ Wf (fp32) ----------
__global__ __launch_bounds__(256) void z_kernel(const float* __restrict__ h,
                                                const float* __restrict__ Wf,
                                                float* __restrict__ z, int M) {
  __shared__ float sW[HID * OUTD];
  int tid = threadIdx.x;
  for (int i = tid; i < HID * OUTD; i += 256) sW[i] = Wf[i];
  __syncthreads();
  int row = blockIdx.x * 256 + tid;
  if (row >= M) return;
  float y[OUTD];
#pragma unroll
  for (int o = 0; o < OUTD; ++o) y[o] = 0.f;
  const float4* hr = (const float4*)(h + (size_t)row * HID);
  for (int k4 = 0; k4 < 32; ++k4) {
    float4 hv = hr[k4];
    int kb = k4 * 4;
#pragma unroll
    for (int o = 0; o < OUTD; ++o) {
      y[o] += hv.x * sW[(kb + 0) * OUTD + o];
      y[o] += hv.y * sW[(kb + 1) * OUTD + o];
      y[o] += hv.z * sW[(kb + 2) * OUTD + o];
      y[o] += hv.w * sW[(kb + 3) * OUTD + o];
    }
  }
#pragma unroll
  for (int o = 0; o < OUTD; ++o) z[(size_t)row * OUTD + o] = y[o];
}

// ---------- last hop in 10-dim + per-graph mean pooling ----------
__global__ __launch_bounds__(256) void agg10_kernel(const float* __restrict__ z,
                                                    const int* __restrict__ fillcnt,
                                                    const int* __restrict__ col_fixed,
                                                    const float* __restrict__ dinv,
                                                    const float* __restrict__ bf,
                                                    const int* __restrict__ ovf_cnt,
                                                    const int* __restrict__ ovf,
                                                    const int* __restrict__ batch,
                                                    float* __restrict__ pool,
                                                    float* __restrict__ cnt,
                                                    const int* __restrict__ flag) {
  __shared__ float spool[NGRAPH * OUTD];
  __shared__ float scount[NGRAPH];
  int tid = threadIdx.x;
  for (int i = tid; i < NGRAPH * OUTD; i += 256) spool[i] = 0.f;
  if (tid < NGRAPH) scount[tid] = 0.f;
  __syncthreads();

  int is64 = flag[0];
  int node = blockIdx.x * 256 + tid;
  bool valid = node < N_NODES;
  int nc = valid ? node : (N_NODES - 1);
  int g = ld_idx(batch, nc, is64);

  float acc[OUTD];
#pragma unroll
  for (int o = 0; o < OUTD; ++o) acc[o] = 0.f;
  float c = 0.f;

  if (valid) {
    float di = dinv[node];
    float sn = di * di;
#pragma unroll
    for (int o = 0; o < OUTD; ++o) acc[o] = z[(size_t)node * OUTD + o] * sn + bf[o];
    c = 1.f;

    int deg = fillcnt[node];
    int m = min(deg, CAP);
    for (int j = 0; j < m; ++j) {
      int src = col_fixed[node * CAP + j];
      float w = dinv[src] * di;
      const float2* zr = (const float2*)(z + (size_t)src * OUTD);
#pragma unroll
      for (int p = 0; p < 5; ++p) {
        float2 u = zr[p];
        acc[2 * p] += u.x * w;
        acc[2 * p + 1] += u.y * w;
      }
    }
    if (deg > CAP) {
      int novf = min(*ovf_cnt, OVF_MAX);
      for (int o = 0; o < novf; ++o) {
        if (ovf[2 * o] == node) {
          int src = ovf[2 * o + 1];
          float w = dinv[src] * di;
#pragma unroll
          for (int qq = 0; qq < OUTD; ++qq) acc[qq] += z[(size_t)src * OUTD + qq] * w;
        }
      }
    }
  }

  int g0 = __builtin_amdgcn_readfirstlane(g);
  unsigned long long same = __ballot(g == g0);
  unsigned long long act = __ballot(1);
  if (same == act) {
#pragma unroll
    for (int off = 1; off < 64; off <<= 1) {
#pragma unroll
      for (int o = 0; o < OUTD; ++o) acc[o] += __shfl_xor(acc[o], off, 64);
      c += __shfl_xor(c, off, 64);
    }
    if ((tid & 63) == 0) {
#pragma unroll
      for (int o = 0; o < OUTD; ++o) atomicAdd(&spool[g0 * OUTD + o], acc[o]);
      atomicAdd(&scount[g0], c);
    }
  } else if (valid) {
#pragma unroll
    for (int o = 0; o < OUTD; ++o) atomicAdd(&spool[g * OUTD + o], acc[o]);
    atomicAdd(&scount[g], 1.f);
  }
  __syncthreads();
  for (int i = tid; i < NGRAPH * OUTD; i += 256) {
    float v = spool[i];
    if (v != 0.f) atomicAdd(&pool[i], v);
  }
  if (tid < NGRAPH && scount[tid] != 0.f) atomicAdd(&cnt[tid], scount[tid]);
}

__global__ void finalize_kernel(const float* __restrict__ pool,
                                const float* __restrict__ cnt,
                                float* __restrict__ out) {
  int i = blockIdx.x * blockDim.x + threadIdx.x;
  if (i < NGRAPH * OUTD) {
    float c = cnt[i / OUTD];
    out[i] = pool[i] / fmaxf(c, 1.0f);
  }
}

extern "C" void kernel_launch(void* const* d_in, const int* in_sizes, int n_in,
                              void* d_out, int out_size, void* d_ws, size_t ws_size,
                              hipStream_t stream) {
  const float* x      = (const float*)d_in[0];
  const int*   ei     = (const int*)d_in[1];
  const int*   batch  = (const int*)d_in[2];
  const float* W_in   = (const float*)d_in[3];
  const float* b_in   = (const float*)d_in[4];
  const float* W_hops = (const float*)d_in[5];
  const float* b_hops = (const float*)d_in[6];
  const float* W_cls  = (const float*)d_in[7];
  const float* b_cls  = (const float*)d_in[8];
  float* out = (float*)d_out;

  char* ws = (char*)d_ws;
  size_t off = 0;
  auto alloc = [&](size_t bytes) -> void* {
    void* p = ws + off;
    off += (bytes + 255) & ~(size_t)255;
    return p;
  };

  // zero-initialized region first
  int*   fillcnt = (int*)alloc(N_NODES * 4);
  int*   ovf_cnt = (int*)alloc(4);
  float* pool    = (float*)alloc(NGRAPH * OUTD * 4);
  float* cnt     = (float*)alloc(NGRAPH * 4);
  size_t zero_bytes = off;
  int*   flag    = (int*)alloc(4);
  float* dinv    = (float*)alloc(N_NODES * 4);
  int*   ovf     = (int*)alloc(OVF_MAX * 2 * 4);
  int*   col_fixed = (int*)alloc((size_t)N_NODES * CAP * 4);
  float* bufA    = (float*)alloc((size_t)N_NODES * HID * 4);
  float* bufB    = (float*)alloc((size_t)N_NODES * HID * 4);
  float* z       = (float*)alloc((size_t)N_NODES * OUTD * 4);
  float* Wf      = (float*)alloc(HID * OUTD * 4);
  float* bf      = (float*)alloc(16 * 4);
  unsigned short* WhiT = (unsigned short*)alloc(4 * HID * HID * 2);
  unsigned short* WloT = (unsigned short*)alloc(4 * HID * HID * 2);
  (void)ws_size; (void)in_sizes; (void)n_in; (void)out_size;

  hipMemsetAsync(d_ws, 0, zero_bytes, stream);
  detect_kernel<<<1, 64, 0, stream>>>(ei, flag);
  prep_kernel<<<4, 256, 0, stream>>>(W_in, W_hops, WhiT, WloT);
  foldw_kernel<<<1, 256, 0, stream>>>(W_hops + 3 * (size_t)HID * HID, W_cls,
                                      b_hops + 3 * HID, b_cls, Wf, bf);

  const int gblocks = (N_NODES + GBM - 1) / GBM;   // 782
  const int EHALF = N_EDGES / 2;                   // 400000
  const int WW = HID * HID;

  // encoder GEMM (bias) + first half of edge placement
  gemm_fill_kernel<<<gblocks, 256, 0, stream>>>(x, WhiT, WloT, b_in, bufA,
                                                ei, fillcnt, col_fixed, ovf_cnt, ovf, flag,
                                                0, EHALF);
  // hop-1 GEMM + second half of edge placement
  gemm_fill_kernel<<<gblocks, 256, 0, stream>>>(bufA, WhiT + WW, WloT + WW, nullptr, bufB,
                                                ei, fillcnt, col_fixed, ovf_cnt, ovf, flag,
                                                EHALF, N_EDGES);
  dinv_kernel<<<(N_NODES + 255) / 256, 256, 0, stream>>>(fillcnt, dinv);

  // hop 1 aggregate
  agg_kernel<<<(N_NODES + 3) / 4, 256, 0, stream>>>(bufB, fillcnt, col_fixed, dinv,
                                                    b_hops, ovf_cnt, ovf, bufA, 1);
  // hops 2..3
  for (int i = 1; i < 3; ++i) {
    gemm_kernel<<<gblocks, 256, 0, stream>>>(bufA, WhiT + (size_t)(i + 1) * WW,
                                             WloT + (size_t)(i + 1) * WW, bufB, N_NODES);
    agg_kernel<<<(N_NODES + 3) / 4, 256, 0, stream>>>(bufB, fillcnt, col_fixed, dinv,
                                                      b_hops + (size_t)i * HID, ovf_cnt, ovf,
                                                      bufA, 1);
  }

  // hop 4 folded through classifier: z = h3 @ (W4@Wc); y = agg(z) + bf; pool
  int nb = (N_NODES + 255) / 256;
  z_kernel<<<nb, 256, 0, stream>>>(bufA, Wf, z, N_NODES);
  agg10_kernel<<<nb, 256, 0, stream>>>(z, fillcnt, col_fixed, dinv, bf,
                                       ovf_cnt, ovf, batch, pool, cnt, flag);
  finalize_kernel<<<(NGRAPH * OUTD + 255) / 256, 256, 0, stream>>>(pool, cnt, out);
}